// Round 1
// baseline (827.693 us; speedup 1.0000x reference)
//
#include <hip/hip_runtime.h>

// ---------------------------------------------------------------------------
// SLMGAE edge scorer, decomposed:
//   fc1 over edges is linear in [zc[s], zc[d]]  =>  precompute per-node
//   P = zc @ fc1_w[0:400] + b1,  Q = zc @ fc1_w[400:800]
//   per edge: h1 = relu(P[s]+Q[d]); h2 = relu(h1@W2+b2); h3 = relu(h2@W3+b3);
//   out = h3@w4 + b4
// Edge GEMMs computed transposed (A = weights, B = activations) so the gather
// produces MFMA B-fragments directly in registers (no LDS for h1).
// ---------------------------------------------------------------------------

using u16 = unsigned short;
using bf16x8 = __attribute__((ext_vector_type(8))) short;  // 8 bf16, 4 VGPRs
using f32x4  = __attribute__((ext_vector_type(4))) float;

#define NN   20000   // nodes
#define NNP  20032   // nodes padded to multiple of 64
#define KD   416     // 400 padded to multiple of 32
#define NE   500000  // edges

#define W1T_N 800    // [800][416]
#define W2T_N 224    // [224][416]  (200 padded)
#define W3T_N 112    // [112][224]  (100 padded)
#define W2T_K 416
#define W3T_K 224

#define W1T_ELEMS (W1T_N*KD)        // 332800
#define W2T_ELEMS (W2T_N*W2T_K)     // 93184
#define W3T_ELEMS (W3T_N*W3T_K)     // 25088

__device__ __forceinline__ u16 f2bf(float f) {           // RNE float->bf16
  unsigned u = __float_as_uint(f);
  u += 0x7fffu + ((u >> 16) & 1u);
  return (u16)(u >> 16);
}
__device__ __forceinline__ float bf2f(u16 s) {
  return __uint_as_float(((unsigned)s) << 16);
}

// ---------------------------------------------------------------------------
// K0: transpose + pad + bf16-convert the classifier weights.
//   W1t[n][k], n<800,k<416:  n<400 -> fc1_w[k][n] ; n>=400 -> fc1_w[400+k][n-400]
//   W2t[n][k] = fc2_w[k][n] (zero-padded), W3t[n][k] = fc3_w[k][n]
// ---------------------------------------------------------------------------
__global__ __launch_bounds__(256) void prep_w(
    const float* __restrict__ fc1, const float* __restrict__ fc2,
    const float* __restrict__ fc3,
    u16* __restrict__ W1t, u16* __restrict__ W2t, u16* __restrict__ W3t)
{
  int idx = blockIdx.x * 256 + threadIdx.x;
  if (idx < W1T_ELEMS) {
    int n = idx / KD, k = idx - n * KD;
    float v = 0.f;
    if (k < 400) v = (n < 400) ? fc1[(size_t)k * 400 + n]
                               : fc1[(size_t)(400 + k) * 400 + (n - 400)];
    W1t[idx] = f2bf(v);
  } else if (idx < W1T_ELEMS + W2T_ELEMS) {
    int r = idx - W1T_ELEMS;
    int n = r / W2T_K, k = r - n * W2T_K;
    float v = (n < 200 && k < 400) ? fc2[(size_t)k * 200 + n] : 0.f;
    W2t[r] = f2bf(v);
  } else if (idx < W1T_ELEMS + W2T_ELEMS + W3T_ELEMS) {
    int r = idx - (W1T_ELEMS + W2T_ELEMS);
    int n = r / W3T_K, k = r - n * W3T_K;
    float v = (n < 100 && k < 200) ? fc3[(size_t)k * 100 + n] : 0.f;
    W3t[r] = f2bf(v);
  }
}

// ---------------------------------------------------------------------------
// K1: per-node tiny MLP (4->64->32->16 fp32) + build zc_bf [NNP][416] bf16
//     zc = [z(64) | m(16) | esm(320) | zeros(16)]
// 256 threads = 4 wave-groups, one node each. 20000 = 5000 blocks * 4 exactly,
// so `real` is uniform per block (no barrier divergence).
// ---------------------------------------------------------------------------
__global__ __launch_bounds__(256) void build_zc(
    const float* __restrict__ z, const float* __restrict__ cell,
    const float* __restrict__ esm,
    const float* __restrict__ w1, const float* __restrict__ b1,
    const float* __restrict__ w2, const float* __restrict__ b2,
    const float* __restrict__ w3, const float* __restrict__ b3,
    u16* __restrict__ zc)
{
  __shared__ float h1s[4][64];
  __shared__ float h2s[4][32];
  __shared__ float ms[4][16];
  int tid = threadIdx.x, g = tid >> 6, t = tid & 63;
  int i = blockIdx.x * 4 + g;
  bool real = (i < NN);
  float c0 = 0, c1 = 0, c2 = 0, c3 = 0;
  if (real) {
    c0 = cell[(size_t)i * 4 + 0]; c1 = cell[(size_t)i * 4 + 1];
    c2 = cell[(size_t)i * 4 + 2]; c3 = cell[(size_t)i * 4 + 3];
  }
  float h = b1[t] + c0 * w1[t] + c1 * w1[64 + t] + c2 * w1[128 + t] + c3 * w1[192 + t];
  h1s[g][t] = fmaxf(h, 0.f);
  __syncthreads();
  if (t < 32) {
    float acc = b2[t];
    #pragma unroll 8
    for (int j = 0; j < 64; j++) acc += h1s[g][j] * w2[j * 32 + t];
    h2s[g][t] = fmaxf(acc, 0.f);
  }
  __syncthreads();
  if (t < 16) {
    float acc = b3[t];
    #pragma unroll 8
    for (int j = 0; j < 32; j++) acc += h2s[g][j] * w3[j * 16 + t];
    ms[g][t] = acc;
  }
  __syncthreads();
  u16* row = zc + (size_t)i * KD;
  for (int k = t; k < KD; k += 64) {
    float v = 0.f;
    if (real) {
      if (k < 64)       v = z[(size_t)i * 64 + k];
      else if (k < 80)  v = ms[g][k - 64];
      else if (k < 400) v = esm[(size_t)i * 320 + (k - 80)];
    }
    row[k] = f2bf(v);
  }
}

// ---------------------------------------------------------------------------
// K2: PQ[NNP][800] = zc_bf[NNP][416] @ W1t^T, bf16 out, fc1_b folded into
// cols 0..399 (the P half). m97-style gemm_bt: A-frags register-resident,
// B streamed from L2. Grid (313, 2): x = 64-row tile, y = 400-col half.
// ---------------------------------------------------------------------------
__global__ __launch_bounds__(256) void node_gemm(
    const u16* __restrict__ zc, const u16* __restrict__ W1t,
    const float* __restrict__ fc1b, u16* __restrict__ PQ)
{
  int tid = threadIdx.x, w = tid >> 6, l = tid & 63, lm = l & 15, quad = l >> 4;
  int mbase = blockIdx.x * 64 + w * 16;
  int nbase = blockIdx.y * 400;

  bf16x8 a[13];
  const u16* arow = zc + (size_t)(mbase + lm) * KD + quad * 8;
  #pragma unroll
  for (int kb = 0; kb < 13; kb++) a[kb] = *(const bf16x8*)(arow + kb * 32);

  for (int nt = 0; nt < 25; nt++) {
    int ncol = nbase + nt * 16 + lm;
    const u16* brow = W1t + (size_t)ncol * KD + quad * 8;
    f32x4 acc = {0.f, 0.f, 0.f, 0.f};
    #pragma unroll
    for (int kb = 0; kb < 13; kb++) {
      bf16x8 b = *(const bf16x8*)(brow + kb * 32);
      acc = __builtin_amdgcn_mfma_f32_16x16x32_bf16(a[kb], b, acc, 0, 0, 0);
    }
    #pragma unroll
    for (int r = 0; r < 4; r++) {
      int row = mbase + quad * 4 + r;          // D row = quad*4+reg
      float v = acc[r] + (ncol < 400 ? fc1b[ncol] : 0.f);  // bias -> P half only
      PQ[(size_t)row * 800 + ncol] = f2bf(v);
    }
  }
}

// ---------------------------------------------------------------------------
// K3: edge kernel. 64 edges/block, 16 edges/wave.
//  Gather: lane computes h1[edge=lane&15][k=kb*32+quad*8 .. +7] = exactly the
//  MFMA B-fragment -> kept in registers (b1[13], 52 VGPRs). fc2 computed as
//  D2' = W2t_asA x h1_asB -> D2'[n2][edge]; transposed through 28.7 KB LDS
//  into B-frag layout for fc3; fc4 = per-lane dot + quad shuffle reduce.
// ---------------------------------------------------------------------------
__global__ __launch_bounds__(256, 4) void edge_kernel(
    const u16* __restrict__ PQ, const u16* __restrict__ W2t,
    const u16* __restrict__ W3t,
    const float* __restrict__ fc2b, const float* __restrict__ fc3b,
    const float* __restrict__ fc4w, const float* __restrict__ fc4b,
    const int* __restrict__ ei, float* __restrict__ out)
{
  __shared__ __align__(16) u16 h2s[4 * 7 * 512];   // 4 waves x 7 k-tiles x 1KiB

  int tid = threadIdx.x, w = tid >> 6, l = tid & 63, lm = l & 15, quad = l >> 4;
  int e = blockIdx.x * 64 + w * 16 + lm;
  int ec = e < NE ? e : NE - 1;
  int s = ei[ec], d = ei[NE + ec];
  const u16* prow = PQ + (size_t)s * 800;        // P half (pre-biased)
  const u16* qrow = PQ + (size_t)d * 800 + 400;  // Q half

  // ---- gather -> B-fragments of h1, in registers --------------------------
  bf16x8 b1f[13];
  #pragma unroll
  for (int kb = 0; kb < 13; kb++) {
    int k = kb * 32 + quad * 8;
    bf16x8 r; 
    if (k < 400) {
      bf16x8 p8 = *(const bf16x8*)(prow + k);
      bf16x8 q8 = *(const bf16x8*)(qrow + k);
      #pragma unroll
      for (int j = 0; j < 8; j++) {
        float v = bf2f((u16)p8[j]) + bf2f((u16)q8[j]);
        r[j] = (short)f2bf(fmaxf(v, 0.f));
      }
    } else {
      #pragma unroll
      for (int j = 0; j < 8; j++) r[j] = 0;
    }
    b1f[kb] = r;
  }

  // ---- fc2: D2'[n2][edge] = W2t x h1, relu, transpose into LDS ------------
  for (int nt = 0; nt < 14; nt++) {
    const u16* wrow = W2t + (size_t)(nt * 16 + lm) * W2T_K + quad * 8;
    f32x4 acc = {0.f, 0.f, 0.f, 0.f};
    #pragma unroll
    for (int kb = 0; kb < 13; kb++) {
      bf16x8 a = *(const bf16x8*)(wrow + kb * 32);
      acc = __builtin_amdgcn_mfma_f32_16x16x32_bf16(a, b1f[kb], acc, 0, 0, 0);
    }
    #pragma unroll
    for (int r = 0; r < 4; r++) {
      int n2 = nt * 16 + quad * 4 + r;           // fc2 output neuron (fc3's k)
      float v = acc[r] + (n2 < 200 ? fc2b[n2] : 0.f);
      v = fmaxf(v, 0.f);
      int k2t = n2 & 31;
      int lanep = (k2t >> 3) * 16 + lm;          // B-frag slot for (k2, edge)
      h2s[(w * 7 + (n2 >> 5)) * 512 + lanep * 8 + (k2t & 7)] = f2bf(v);
    }
  }

  __syncthreads();   // cross-lane LDS visibility (transpose within wave)

  // ---- fc3 + fc4 -----------------------------------------------------------
  bf16x8 b2f[7];
  #pragma unroll
  for (int kb = 0; kb < 7; kb++)
    b2f[kb] = *(const bf16x8*)&h2s[(w * 7 + kb) * 512 + l * 8];

  float osum = 0.f;
  for (int nt3 = 0; nt3 < 7; nt3++) {
    const u16* wrow = W3t + (size_t)(nt3 * 16 + lm) * W3T_K + quad * 8;
    f32x4 acc = {0.f, 0.f, 0.f, 0.f};
    #pragma unroll
    for (int kb = 0; kb < 7; kb++) {
      bf16x8 a = *(const bf16x8*)(wrow + kb * 32);
      acc = __builtin_amdgcn_mfma_f32_16x16x32_bf16(a, b2f[kb], acc, 0, 0, 0);
    }
    #pragma unroll
    for (int r = 0; r < 4; r++) {
      int n3 = nt3 * 16 + quad * 4 + r;
      if (n3 < 100) {
        float v = fmaxf(acc[r] + fc3b[n3], 0.f);
        osum += v * fc4w[n3];
      }
    }
  }
  // sum partials across the 4 quads holding this edge's column
  osum += __shfl_xor(osum, 16);
  osum += __shfl_xor(osum, 32);
  if (quad == 0 && e < NE) out[e] = osum + fc4b[0];
}

// ---------------------------------------------------------------------------
extern "C" void kernel_launch(void* const* d_in, const int* in_sizes, int n_in,
                              void* d_out, int out_size, void* d_ws, size_t ws_size,
                              hipStream_t stream) {
  (void)in_sizes; (void)n_in; (void)out_size; (void)ws_size;
  const float* z    = (const float*)d_in[0];
  const int*   ei   = (const int*)d_in[1];
  const float* cell = (const float*)d_in[2];
  const float* esm  = (const float*)d_in[3];
  const float* w1   = (const float*)d_in[4];
  const float* b1   = (const float*)d_in[5];
  const float* w2   = (const float*)d_in[6];
  const float* b2   = (const float*)d_in[7];
  const float* w3   = (const float*)d_in[8];
  const float* b3   = (const float*)d_in[9];
  const float* fc1w = (const float*)d_in[10];
  const float* fc1b = (const float*)d_in[11];
  const float* fc2w = (const float*)d_in[12];
  const float* fc2b = (const float*)d_in[13];
  const float* fc3w = (const float*)d_in[14];
  const float* fc3b = (const float*)d_in[15];
  const float* fc4w = (const float*)d_in[16];
  const float* fc4b = (const float*)d_in[17];
  float* out = (float*)d_out;

  // workspace layout (all 16B-aligned): ~47.3 MB total
  u16* zc  = (u16*)d_ws;                       // NNP*416 bf16
  u16* PQ  = zc  + (size_t)NNP * KD;           // NNP*800 bf16
  u16* W1t = PQ  + (size_t)NNP * 800;          // 332800
  u16* W2t = W1t + W1T_ELEMS;                  // 93184
  u16* W3t = W2t + W2T_ELEMS;                  // 25088

  const int prep_elems = W1T_ELEMS + W2T_ELEMS + W3T_ELEMS;   // 451072
  prep_w<<<(prep_elems + 255) / 256, 256, 0, stream>>>(fc1w, fc2w, fc3w, W1t, W2t, W3t);
  build_zc<<<NNP / 4, 256, 0, stream>>>(z, cell, esm, w1, b1, w2, b2, w3, b3, zc);
  node_gemm<<<dim3(NNP / 64, 2), 256, 0, stream>>>(zc, W1t, fc1b, PQ);
  edge_kernel<<<(NE + 63) / 64, 256, 0, stream>>>(PQ, W2t, W3t, fc2b, fc3b, fc4w, fc4b, ei, out);
}

// Round 2
// 664.575 us; speedup vs baseline: 1.2454x; 1.2454x over previous
//
#include <hip/hip_runtime.h>

// ---------------------------------------------------------------------------
// SLMGAE edge scorer, round 2.
//   P = zc @ fc1_w[0:400] + b1,  Q = zc @ fc1_w[400:800]   (per node)
//   per edge: h1 = relu(P[s]+Q[d]); h2 = relu(h1@W2+b2); h3 = relu(h2@W3+b3);
//   out = h3@w4 + b4
// Round-2 changes vs round 1:
//   * edge kernel: 32 edges/wave via mfma_f32_32x32x16_bf16 (halves weight
//     L2 streaming per edge: 14.75 -> 7.6 KB/edge), ZERO LDS, no barriers.
//   * h2 transpose (C-layout -> B-frag) done with shfl_xor(32)+select.
//   * all biases folded into MFMA via constant-1.0 K-columns (k=400 col of
//     W1t/W2t holds fc1b/fc2b; k2=200 col of W3t holds fc3b).
//   * node_gemm: dual 16-row A-tiles per wave (halves W1t streaming).
// ---------------------------------------------------------------------------

using u16    = unsigned short;
using bf16x8 = __attribute__((ext_vector_type(8))) short;   // 8 bf16 (4 VGPR)
using f32x4  = __attribute__((ext_vector_type(4))) float;
using f32x16 = __attribute__((ext_vector_type(16))) float;
using i32x4  = __attribute__((ext_vector_type(4))) int;

#define NN   20000   // nodes
#define NNP  20032   // nodes padded (multiple of 64)
#define KD   416     // 400 padded to multiple of 32 (col 400 = bias-one)
#define NE   500000  // edges

#define W2T_K 416    // fc2 K (400 real + bias col 400)
#define W3T_K 224    // fc3 K (200 real + bias col 200)
#define W1T_ELEMS (800*KD)       // 332800
#define W2T_ELEMS (224*W2T_K)    // 93184
#define W3T_ELEMS (128*W3T_K)    // 28672  (fc3 N padded 100->128)
#define F4_ELEMS  128
#define PREP_TOT  (W1T_ELEMS + W2T_ELEMS + W3T_ELEMS + F4_ELEMS)

__device__ __forceinline__ u16 f2bf(float f) {              // RNE f32->bf16
  unsigned u = __float_as_uint(f);
  u += 0x7fffu + ((u >> 16) & 1u);
  return (u16)(u >> 16);
}

// ---------------------------------------------------------------------------
// K0: weight prep (transpose + pad + bf16 + bias columns).
//  W1t[n][k] n<800,k<416: k<400 -> fc1 halves; k==400 -> fc1b[n] (n<400) else 0
//  W2t[n][k] n<224:       k<400 -> fc2_w[k][n]; k==400 -> fc2b[n]  (n<200)
//  W3t[n][k] n<128:       k<200 -> fc3_w[k][n]; k==200 -> fc3b[n]  (n<100)
//  fc4wp[128] f32 = fc4_w zero-padded
// ---------------------------------------------------------------------------
__global__ __launch_bounds__(256) void prep_w(
    const float* __restrict__ fc1, const float* __restrict__ fc1b,
    const float* __restrict__ fc2, const float* __restrict__ fc2b,
    const float* __restrict__ fc3, const float* __restrict__ fc3b,
    const float* __restrict__ fc4,
    u16* __restrict__ W1t, u16* __restrict__ W2t, u16* __restrict__ W3t,
    float* __restrict__ fc4wp)
{
  int idx = blockIdx.x * 256 + threadIdx.x;
  if (idx < W1T_ELEMS) {
    int n = idx / KD, k = idx - n * KD;
    float v = 0.f;
    if (k < 400) v = (n < 400) ? fc1[(size_t)k * 400 + n]
                               : fc1[(size_t)(400 + k) * 400 + (n - 400)];
    else if (k == 400 && n < 400) v = fc1b[n];
    W1t[idx] = f2bf(v);
  } else if (idx < W1T_ELEMS + W2T_ELEMS) {
    int r = idx - W1T_ELEMS;
    int n = r / W2T_K, k = r - n * W2T_K;
    float v = 0.f;
    if (n < 200) {
      if (k < 400) v = fc2[(size_t)k * 200 + n];
      else if (k == 400) v = fc2b[n];
    }
    W2t[r] = f2bf(v);
  } else if (idx < W1T_ELEMS + W2T_ELEMS + W3T_ELEMS) {
    int r = idx - (W1T_ELEMS + W2T_ELEMS);
    int n = r / W3T_K, k = r - n * W3T_K;
    float v = 0.f;
    if (n < 100) {
      if (k < 200) v = fc3[(size_t)k * 100 + n];
      else if (k == 200) v = fc3b[n];
    }
    W3t[r] = f2bf(v);
  } else if (idx < PREP_TOT) {
    int r = idx - (W1T_ELEMS + W2T_ELEMS + W3T_ELEMS);
    fc4wp[r] = (r < 100) ? fc4[r] : 0.f;
  }
}

// ---------------------------------------------------------------------------
// K1: per-node tiny MLP (4->64->32->16 fp32) + build zc_bf [NNP][416]
//     zc = [z(64) | m(16) | esm(320) | 1.0 at k=400 | zeros]
// ---------------------------------------------------------------------------
__global__ __launch_bounds__(256) void build_zc(
    const float* __restrict__ z, const float* __restrict__ cell,
    const float* __restrict__ esm,
    const float* __restrict__ w1, const float* __restrict__ b1,
    const float* __restrict__ w2, const float* __restrict__ b2,
    const float* __restrict__ w3, const float* __restrict__ b3,
    u16* __restrict__ zc)
{
  __shared__ float h1s[4][64];
  __shared__ float h2s[4][32];
  __shared__ float ms[4][16];
  int tid = threadIdx.x, g = tid >> 6, t = tid & 63;
  int i = blockIdx.x * 4 + g;
  bool real = (i < NN);
  float c0 = 0, c1 = 0, c2 = 0, c3 = 0;
  if (real) {
    c0 = cell[(size_t)i * 4 + 0]; c1 = cell[(size_t)i * 4 + 1];
    c2 = cell[(size_t)i * 4 + 2]; c3 = cell[(size_t)i * 4 + 3];
  }
  float h = b1[t] + c0 * w1[t] + c1 * w1[64 + t] + c2 * w1[128 + t] + c3 * w1[192 + t];
  h1s[g][t] = fmaxf(h, 0.f);
  __syncthreads();
  if (t < 32) {
    float acc = b2[t];
    #pragma unroll 8
    for (int j = 0; j < 64; j++) acc += h1s[g][j] * w2[j * 32 + t];
    h2s[g][t] = fmaxf(acc, 0.f);
  }
  __syncthreads();
  if (t < 16) {
    float acc = b3[t];
    #pragma unroll 8
    for (int j = 0; j < 32; j++) acc += h2s[g][j] * w3[j * 16 + t];
    ms[g][t] = acc;
  }
  __syncthreads();
  u16* row = zc + (size_t)i * KD;
  for (int k = t; k < KD; k += 64) {
    float v = 0.f;
    if (real) {
      if (k < 64)       v = z[(size_t)i * 64 + k];
      else if (k < 80)  v = ms[g][k - 64];
      else if (k < 400) v = esm[(size_t)i * 320 + (k - 80)];
      else if (k == 400) v = 1.0f;     // bias-one column (fc1b lives in W1t)
    }
    row[k] = f2bf(v);
  }
}

// ---------------------------------------------------------------------------
// K2: PQ[NNP][800] = zc_bf @ W1t^T (bias via k=400 col), bf16 out.
// Dual 16-row A-tiles per wave (32 rows) share each streamed B fragment.
// Grid (ceil(NNP/128), 2); last block row-clamps loads, guards stores.
// ---------------------------------------------------------------------------
__global__ __launch_bounds__(256) void node_gemm(
    const u16* __restrict__ zc, const u16* __restrict__ W1t,
    u16* __restrict__ PQ)
{
  int tid = threadIdx.x, w = tid >> 6, l = tid & 63, lm = l & 15, quad = l >> 4;
  int mbase = blockIdx.x * 128 + w * 32;
  int nbase = blockIdx.y * 400;

  int ra = mbase + lm;       if (ra > NNP - 1) ra = NNP - 1;
  int rb = mbase + 16 + lm;  if (rb > NNP - 1) rb = NNP - 1;
  bf16x8 a0[13], a1[13];
  const u16* arow0 = zc + (size_t)ra * KD + quad * 8;
  const u16* arow1 = zc + (size_t)rb * KD + quad * 8;
  #pragma unroll
  for (int kb = 0; kb < 13; kb++) {
    a0[kb] = *(const bf16x8*)(arow0 + kb * 32);
    a1[kb] = *(const bf16x8*)(arow1 + kb * 32);
  }

  for (int nt = 0; nt < 25; nt++) {
    int ncol = nbase + nt * 16 + lm;
    const u16* brow = W1t + (size_t)ncol * KD + quad * 8;
    f32x4 acc0 = {0.f, 0.f, 0.f, 0.f};
    f32x4 acc1 = {0.f, 0.f, 0.f, 0.f};
    #pragma unroll
    for (int kb = 0; kb < 13; kb++) {
      bf16x8 b = *(const bf16x8*)(brow + kb * 32);
      acc0 = __builtin_amdgcn_mfma_f32_16x16x32_bf16(a0[kb], b, acc0, 0, 0, 0);
      acc1 = __builtin_amdgcn_mfma_f32_16x16x32_bf16(a1[kb], b, acc1, 0, 0, 0);
    }
    #pragma unroll
    for (int r = 0; r < 4; r++) {
      int row0 = mbase + quad * 4 + r;
      int row1 = row0 + 16;
      if (row0 < NNP) PQ[(size_t)row0 * 800 + ncol] = f2bf(acc0[r]);
      if (row1 < NNP) PQ[(size_t)row1 * 800 + ncol] = f2bf(acc1[r]);
    }
  }
}

// ---------------------------------------------------------------------------
// K3: edge kernel — 32 edges per wave, mfma 32x32x16, zero LDS, no barriers.
//   32x32x16 layouts: A[m=lane&31][k=8h+j], B[k=8h+j][n=lane&31] (h=lane>>5),
//   C/D: col=lane&31, row=(reg&3)+8*(reg>>2)+4h.
//   Gather builds h1 B-frags directly; fc2 = W2t(A) x h1(B); h2 kept packed
//   in regs; shfl_xor(32)+select rebuilds fc3 B-frags; fc4 = dot + xor-32.
// ---------------------------------------------------------------------------
__global__ __launch_bounds__(256, 2) void edge_kernel(
    const u16* __restrict__ PQ, const u16* __restrict__ W2t,
    const u16* __restrict__ W3t, const float* __restrict__ fc4wp,
    const float* __restrict__ fc4b,
    const int* __restrict__ ei, float* __restrict__ out)
{
  int tid = threadIdx.x, w = tid >> 6, l = tid & 63;
  int c = l & 31, h = l >> 5;
  int e = blockIdx.x * 128 + w * 32 + c;
  int ec = e < NE ? e : NE - 1;
  int s = ei[ec], d = ei[NE + ec];
  const u16* prow = PQ + (size_t)s * 800 + h * 8;        // P (pre-biased)
  const u16* qrow = PQ + (size_t)d * 800 + 400 + h * 8;  // Q

  // ---- gather -> h1 B-frags (kb 0..24 real; kb 25 = bias-one) -------------
  i32x4 h1i[25];
  #pragma unroll
  for (int kb = 0; kb < 25; kb++) {
    i32x4 pv = *(const i32x4*)(prow + kb * 16);
    i32x4 qv = *(const i32x4*)(qrow + kb * 16);
    i32x4 r;
    #pragma unroll
    for (int j2 = 0; j2 < 4; j2++) {
      unsigned pu = (unsigned)pv[j2], qu = (unsigned)qv[j2];
      float lo = __uint_as_float(pu << 16) + __uint_as_float(qu << 16);
      float hi = __uint_as_float(pu & 0xFFFF0000u) + __uint_as_float(qu & 0xFFFF0000u);
      lo = fmaxf(lo, 0.f);
      hi = fmaxf(hi, 0.f);
      unsigned ul = __float_as_uint(lo); ul += 0x7fffu + ((ul >> 16) & 1u);
      unsigned uh = __float_as_uint(hi); uh += 0x7fffu + ((uh >> 16) & 1u);
      r[j2] = (int)((ul >> 16) | (uh & 0xFFFF0000u));
    }
    h1i[kb] = r;
  }
  i32x4 bias1 = {0, 0, 0, 0};
  if (h == 0) bias1[0] = 0x3f80;   // h1[k=400] = 1.0 (bf16) for every edge

  // ---- fc2: 7 ntiles of 32 neurons; h2 packed bf16-pairs in regs ----------
  int p2[7][8];
  #pragma unroll
  for (int nt = 0; nt < 7; nt++) {
    const u16* wr = W2t + (size_t)(nt * 32 + c) * W2T_K + h * 8;
    f32x16 acc = {0.f,0.f,0.f,0.f,0.f,0.f,0.f,0.f,0.f,0.f,0.f,0.f,0.f,0.f,0.f,0.f};
    #pragma unroll
    for (int kb = 0; kb < 25; kb++) {
      bf16x8 a = *(const bf16x8*)(wr + kb * 16);
      acc = __builtin_amdgcn_mfma_f32_32x32x16_bf16(
          a, __builtin_bit_cast(bf16x8, h1i[kb]), acc, 0, 0, 0);
    }
    {  // kb = 25: bias column k=400
      bf16x8 a = *(const bf16x8*)(wr + 25 * 16);
      acc = __builtin_amdgcn_mfma_f32_32x32x16_bf16(
          a, __builtin_bit_cast(bf16x8, bias1), acc, 0, 0, 0);
    }
    #pragma unroll
    for (int q = 0; q < 8; q++) {   // relu + RNE-pack regs (2q, 2q+1)
      float v0 = fmaxf(acc[2 * q], 0.f);
      float v1 = fmaxf(acc[2 * q + 1], 0.f);
      unsigned u0 = __float_as_uint(v0); u0 += 0x7fffu + ((u0 >> 16) & 1u);
      unsigned u1 = __float_as_uint(v1); u1 += 0x7fffu + ((u1 >> 16) & 1u);
      p2[nt][q] = (int)((u0 >> 16) | (u1 & 0xFFFF0000u));
    }
  }

  // ---- transpose: C-layout h2 -> fc3 B-frags via shfl_xor(32) -------------
  // target dword jj of frag kb3 holds k2 = kb3*16 + 8h + {2jj, 2jj+1};
  // source packed reg q(h) = (jj&1) + 4*(kb3&1) + 2h, source half = (jj>>1).
  i32x4 b2f[14];
  #pragma unroll
  for (int kb3 = 0; kb3 < 14; kb3++) {
    int nt = kb3 >> 1;
    i32x4 f;
    #pragma unroll
    for (int jj = 0; jj < 4; jj++) {
      int q0 = (jj & 1) + 4 * (kb3 & 1);
      if (jj < 2) {        // source lives in lower half (h_s = 0)
        int x = __shfl_xor(p2[nt][q0 + 2], 32);
        f[jj] = h ? x : p2[nt][q0];
      } else {             // source lives in upper half (h_s = 1)
        int y = __shfl_xor(p2[nt][q0], 32);
        f[jj] = h ? p2[nt][q0 + 2] : y;
      }
    }
    if (kb3 == 12 && h) f[0] |= 0x3f80;   // h2[k2=200] = 1.0 (fc3 bias-one)
    b2f[kb3] = f;
  }

  // ---- fc3 + fc4 ----------------------------------------------------------
  float osum = 0.f;
  for (int nt3 = 0; nt3 < 4; nt3++) {
    const u16* wr = W3t + (size_t)(nt3 * 32 + c) * W3T_K + h * 8;
    f32x16 acc = {0.f,0.f,0.f,0.f,0.f,0.f,0.f,0.f,0.f,0.f,0.f,0.f,0.f,0.f,0.f,0.f};
    #pragma unroll
    for (int kb3 = 0; kb3 < 14; kb3++) {
      bf16x8 a = *(const bf16x8*)(wr + kb3 * 16);
      acc = __builtin_amdgcn_mfma_f32_32x32x16_bf16(
          a, __builtin_bit_cast(bf16x8, b2f[kb3]), acc, 0, 0, 0);
    }
    #pragma unroll
    for (int r = 0; r < 16; r++) {
      int rho = (r & 3) + 8 * (r >> 2) + 4 * h + 32 * nt3;
      osum += fmaxf(acc[r], 0.f) * fc4wp[rho];   // pad rows: 0 * 0
    }
  }
  osum += __shfl_xor(osum, 32);     // combine the two k-halves of this edge
  if (h == 0 && e < NE) out[e] = osum + fc4b[0];
}

// ---------------------------------------------------------------------------
extern "C" void kernel_launch(void* const* d_in, const int* in_sizes, int n_in,
                              void* d_out, int out_size, void* d_ws, size_t ws_size,
                              hipStream_t stream) {
  (void)in_sizes; (void)n_in; (void)out_size; (void)ws_size;
  const float* z    = (const float*)d_in[0];
  const int*   ei   = (const int*)d_in[1];
  const float* cell = (const float*)d_in[2];
  const float* esm  = (const float*)d_in[3];
  const float* w1   = (const float*)d_in[4];
  const float* b1   = (const float*)d_in[5];
  const float* w2   = (const float*)d_in[6];
  const float* b2   = (const float*)d_in[7];
  const float* w3   = (const float*)d_in[8];
  const float* b3   = (const float*)d_in[9];
  const float* fc1w = (const float*)d_in[10];
  const float* fc1b = (const float*)d_in[11];
  const float* fc2w = (const float*)d_in[12];
  const float* fc2b = (const float*)d_in[13];
  const float* fc3w = (const float*)d_in[14];
  const float* fc3b = (const float*)d_in[15];
  const float* fc4w = (const float*)d_in[16];
  const float* fc4b = (const float*)d_in[17];
  float* out = (float*)d_out;

  // workspace layout (u16 units, all 16B-aligned): ~49.6 MB
  u16* zc  = (u16*)d_ws;                        // NNP*416
  u16* PQ  = zc  + (size_t)NNP * KD;            // NNP*800
  u16* W1t = PQ  + (size_t)NNP * 800;           // 332800
  u16* W2t = W1t + W1T_ELEMS;                   // 93184
  u16* W3t = W2t + W2T_ELEMS;                   // 28672
  float* fc4wp = (float*)(W3t + W3T_ELEMS);     // 128 f32

  prep_w<<<(PREP_TOT + 255) / 256, 256, 0, stream>>>(
      fc1w, fc1b, fc2w, fc2b, fc3w, fc3b, fc4w, W1t, W2t, W3t, fc4wp);
  build_zc<<<NNP / 4, 256, 0, stream>>>(z, cell, esm, w1, b1, w2, b2, w3, b3, zc);
  node_gemm<<<dim3((NNP + 127) / 128, 2), 256, 0, stream>>>(zc, W1t, PQ);
  edge_kernel<<<(NE + 127) / 128, 256, 0, stream>>>(PQ, W2t, W3t, fc4wp, fc4b, ei, out);
}

// Round 3
// 474.673 us; speedup vs baseline: 1.7437x; 1.4001x over previous
//
#include <hip/hip_runtime.h>

// ---------------------------------------------------------------------------
// SLMGAE edge scorer, round 3.
//   P = zc @ fc1_w[0:400] + b1,  Q = zc @ fc1_w[400:800]   (per node)
//   per edge: h1 = relu(P[s]+Q[d]); h2 = relu(h1@W2+b2); h3 = relu(h2@W3+b3);
//   out = h3@w4 + b4
// Round-3 changes vs round 2 (which was transaction-rate bound: every weight
// A-fragment load strided 832 B across lanes = 64-line scatter per load):
//   * ALL weight operands stored in MFMA fragment order [tile][kb][lane][8]
//     -> every weight load is one coalesced 1 KB wave transaction.
//   * edge kernel stages each weight tile into LDS once per BLOCK (frag-order
//     makes both the staging load and ds_read conflict-benign) -> weight L2
//     traffic 3.8 GB -> 0.95 GB.
//   * node_gemm B-operand (W1) also frag-ordered.
// ---------------------------------------------------------------------------

using u16    = unsigned short;
using bf16x8 = __attribute__((ext_vector_type(8))) short;   // 8 bf16 (4 VGPR)
using f32x4  = __attribute__((ext_vector_type(4))) float;
using f32x16 = __attribute__((ext_vector_type(16))) float;
using i32x4  = __attribute__((ext_vector_type(4))) int;

#define NN   20000   // nodes
#define NNP  20032   // nodes padded (multiple of 64)
#define KD   416     // 400 padded to multiple of 32 (col 400 = bias-one)
#define NE   500000  // edges

// fragment-order element counts
#define W1F_ELEMS (50*13*512)    // 50 n-tiles(16) x 13 kb(32) x 64 lanes x 8
#define W2F_ELEMS (7*26*512)     // 7 n-tiles(32) x 26 kb(16) x 64 x 8
#define W3F_ELEMS (4*14*512)     // 4 n-tiles(32) x 14 kb(16) x 64 x 8
#define F4_ELEMS  128
#define PREP_TOT  (W1F_ELEMS + W2F_ELEMS + W3F_ELEMS + F4_ELEMS)

__device__ __forceinline__ u16 f2bf(float f) {              // RNE f32->bf16
  unsigned u = __float_as_uint(f);
  u += 0x7fffu + ((u >> 16) & 1u);
  return (u16)(u >> 16);
}

// ---------------------------------------------------------------------------
// K0: weight prep — transpose + pad + bf16 + bias columns, FRAGMENT ORDER.
//  W1f[g][kb][l][j] = W1t[n=g*16+(l&15)][k=kb*32+(l>>4)*8+j]   (16x16x32 B-frag)
//    W1t[n][k]: k<400 -> fc1 halves; k==400 -> fc1b[n] (n<400); else 0
//  W2f[nt][kb][l][j] = W2t[n=nt*32+(l&31)][k=kb*16+(l>>5)*8+j] (32x32x16 A-frag)
//    W2t[n][k]: n<200: k<400 -> fc2_w[k][n]; k==400 -> fc2b[n]; else 0
//  W3f[nt][kb][l][j] = W3t[n=nt*32+(l&31)][k=kb*16+(l>>5)*8+j]
//    W3t[n][k]: n<100: k<200 -> fc3_w[k][n]; k==200 -> fc3b[n]; else 0
// ---------------------------------------------------------------------------
__global__ __launch_bounds__(256) void prep_w(
    const float* __restrict__ fc1, const float* __restrict__ fc1b,
    const float* __restrict__ fc2, const float* __restrict__ fc2b,
    const float* __restrict__ fc3, const float* __restrict__ fc3b,
    const float* __restrict__ fc4,
    u16* __restrict__ W1f, u16* __restrict__ W2f, u16* __restrict__ W3f,
    float* __restrict__ fc4wp)
{
  int idx = blockIdx.x * 256 + threadIdx.x;
  if (idx < W1F_ELEMS) {
    int j = idx & 7, l = (idx >> 3) & 63, t = idx >> 9;
    int kb = t % 13, g = t / 13;
    int n = g * 16 + (l & 15);
    int k = kb * 32 + (l >> 4) * 8 + j;
    float v = 0.f;
    if (k < 400) v = (n < 400) ? fc1[(size_t)k * 400 + n]
                               : fc1[(size_t)(400 + k) * 400 + (n - 400)];
    else if (k == 400 && n < 400) v = fc1b[n];
    W1f[idx] = f2bf(v);
  } else if (idx < W1F_ELEMS + W2F_ELEMS) {
    int r = idx - W1F_ELEMS;
    int j = r & 7, l = (r >> 3) & 63, t = r >> 9;
    int kb = t % 26, nt = t / 26;
    int n = nt * 32 + (l & 31);
    int k = kb * 16 + (l >> 5) * 8 + j;
    float v = 0.f;
    if (n < 200) {
      if (k < 400) v = fc2[(size_t)k * 200 + n];
      else if (k == 400) v = fc2b[n];
    }
    W2f[r] = f2bf(v);
  } else if (idx < W1F_ELEMS + W2F_ELEMS + W3F_ELEMS) {
    int r = idx - (W1F_ELEMS + W2F_ELEMS);
    int j = r & 7, l = (r >> 3) & 63, t = r >> 9;
    int kb = t % 14, nt = t / 14;
    int n = nt * 32 + (l & 31);
    int k = kb * 16 + (l >> 5) * 8 + j;
    float v = 0.f;
    if (n < 100) {
      if (k < 200) v = fc3[(size_t)k * 100 + n];
      else if (k == 200) v = fc3b[n];
    }
    W3f[r] = f2bf(v);
  } else if (idx < PREP_TOT) {
    int r = idx - (W1F_ELEMS + W2F_ELEMS + W3F_ELEMS);
    fc4wp[r] = (r < 100) ? fc4[r] : 0.f;
  }
}

// ---------------------------------------------------------------------------
// K1: per-node tiny MLP (4->64->32->16 fp32) + build zc_bf [NNP][416]
//     zc = [z(64) | m(16) | esm(320) | 1.0 at k=400 | zeros]
// ---------------------------------------------------------------------------
__global__ __launch_bounds__(256) void build_zc(
    const float* __restrict__ z, const float* __restrict__ cell,
    const float* __restrict__ esm,
    const float* __restrict__ w1, const float* __restrict__ b1,
    const float* __restrict__ w2, const float* __restrict__ b2,
    const float* __restrict__ w3, const float* __restrict__ b3,
    u16* __restrict__ zc)
{
  __shared__ float h1s[4][64];
  __shared__ float h2s[4][32];
  __shared__ float ms[4][16];
  int tid = threadIdx.x, g = tid >> 6, t = tid & 63;
  int i = blockIdx.x * 4 + g;
  bool real = (i < NN);
  float c0 = 0, c1 = 0, c2 = 0, c3 = 0;
  if (real) {
    c0 = cell[(size_t)i * 4 + 0]; c1 = cell[(size_t)i * 4 + 1];
    c2 = cell[(size_t)i * 4 + 2]; c3 = cell[(size_t)i * 4 + 3];
  }
  float h = b1[t] + c0 * w1[t] + c1 * w1[64 + t] + c2 * w1[128 + t] + c3 * w1[192 + t];
  h1s[g][t] = fmaxf(h, 0.f);
  __syncthreads();
  if (t < 32) {
    float acc = b2[t];
    #pragma unroll 8
    for (int j = 0; j < 64; j++) acc += h1s[g][j] * w2[j * 32 + t];
    h2s[g][t] = fmaxf(acc, 0.f);
  }
  __syncthreads();
  if (t < 16) {
    float acc = b3[t];
    #pragma unroll 8
    for (int j = 0; j < 32; j++) acc += h2s[g][j] * w3[j * 16 + t];
    ms[g][t] = acc;
  }
  __syncthreads();
  u16* row = zc + (size_t)i * KD;
  for (int k = t; k < KD; k += 64) {
    float v = 0.f;
    if (real) {
      if (k < 64)       v = z[(size_t)i * 64 + k];
      else if (k < 80)  v = ms[g][k - 64];
      else if (k < 400) v = esm[(size_t)i * 320 + (k - 80)];
      else if (k == 400) v = 1.0f;     // bias-one column (fc1b lives in W1f)
    }
    row[k] = f2bf(v);
  }
}

// ---------------------------------------------------------------------------
// K2: PQ[NNP][800] = zc_bf @ W1^T (bias via k=400 col), bf16 out.
// Dual 16-row A-tiles per wave; B streamed from frag-ordered W1f (coalesced).
// ---------------------------------------------------------------------------
__global__ __launch_bounds__(256) void node_gemm(
    const u16* __restrict__ zc, const u16* __restrict__ W1f,
    u16* __restrict__ PQ)
{
  int tid = threadIdx.x, w = tid >> 6, l = tid & 63, lm = l & 15, quad = l >> 4;
  int mbase = blockIdx.x * 128 + w * 32;
  int nbase = blockIdx.y * 400;

  int ra = mbase + lm;       if (ra > NNP - 1) ra = NNP - 1;
  int rb = mbase + 16 + lm;  if (rb > NNP - 1) rb = NNP - 1;
  bf16x8 a0[13], a1[13];
  const u16* arow0 = zc + (size_t)ra * KD + quad * 8;
  const u16* arow1 = zc + (size_t)rb * KD + quad * 8;
  #pragma unroll
  for (int kb = 0; kb < 13; kb++) {
    a0[kb] = *(const bf16x8*)(arow0 + kb * 32);
    a1[kb] = *(const bf16x8*)(arow1 + kb * 32);
  }

  for (int nt = 0; nt < 25; nt++) {
    int g = blockIdx.y * 25 + nt;          // global 16-col tile of the 800
    int ncol = nbase + nt * 16 + lm;
    const u16* bbase = W1f + ((size_t)g * 13 * 64 + l) * 8;
    f32x4 acc0 = {0.f, 0.f, 0.f, 0.f};
    f32x4 acc1 = {0.f, 0.f, 0.f, 0.f};
    #pragma unroll
    for (int kb = 0; kb < 13; kb++) {
      bf16x8 b = *(const bf16x8*)(bbase + (size_t)kb * 512);
      acc0 = __builtin_amdgcn_mfma_f32_16x16x32_bf16(a0[kb], b, acc0, 0, 0, 0);
      acc1 = __builtin_amdgcn_mfma_f32_16x16x32_bf16(a1[kb], b, acc1, 0, 0, 0);
    }
    #pragma unroll
    for (int r = 0; r < 4; r++) {
      int row0 = mbase + quad * 4 + r;
      int row1 = row0 + 16;
      if (row0 < NNP) PQ[(size_t)row0 * 800 + ncol] = f2bf(acc0[r]);
      if (row1 < NNP) PQ[(size_t)row1 * 800 + ncol] = f2bf(acc1[r]);
    }
  }
}

// ---------------------------------------------------------------------------
// K3: edge kernel — 32 edges/wave, mfma 32x32x16, weights LDS-staged/block.
//   Gather builds h1 B-frags in registers; fc2 = W2(A,LDS) x h1(B);
//   h2 -> fc3 B-frags via shfl_xor(32); fc4 = dot + xor-32 reduce.
// ---------------------------------------------------------------------------
__global__ __launch_bounds__(256, 2) void edge_kernel(
    const u16* __restrict__ PQ, const u16* __restrict__ W2f,
    const u16* __restrict__ W3f, const float* __restrict__ fc4wp,
    const float* __restrict__ fc4b,
    const int* __restrict__ ei, float* __restrict__ out)
{
  __shared__ __align__(16) u16 wsm[26 * 512];   // 26.6 KB weight-tile stage

  int tid = threadIdx.x, w = tid >> 6, l = tid & 63;
  int c = l & 31, h = l >> 5;
  int e = blockIdx.x * 128 + w * 32 + c;
  int ec = e < NE ? e : NE - 1;
  int s = ei[ec], d = ei[NE + ec];
  const u16* prow = PQ + (size_t)s * 800 + h * 8;        // P (pre-biased)
  const u16* qrow = PQ + (size_t)d * 800 + 400 + h * 8;  // Q

  // ---- gather -> h1 B-frags (kb 0..24 real; kb 25 = bias-one) -------------
  i32x4 h1i[25];
  #pragma unroll
  for (int kb = 0; kb < 25; kb++) {
    i32x4 pv = *(const i32x4*)(prow + kb * 16);
    i32x4 qv = *(const i32x4*)(qrow + kb * 16);
    i32x4 r;
    #pragma unroll
    for (int j2 = 0; j2 < 4; j2++) {
      unsigned pu = (unsigned)pv[j2], qu = (unsigned)qv[j2];
      float lo = __uint_as_float(pu << 16) + __uint_as_float(qu << 16);
      float hi = __uint_as_float(pu & 0xFFFF0000u) + __uint_as_float(qu & 0xFFFF0000u);
      lo = fmaxf(lo, 0.f);
      hi = fmaxf(hi, 0.f);
      unsigned ul = __float_as_uint(lo); ul += 0x7fffu + ((ul >> 16) & 1u);
      unsigned uh = __float_as_uint(hi); uh += 0x7fffu + ((uh >> 16) & 1u);
      r[j2] = (int)((ul >> 16) | (uh & 0xFFFF0000u));
    }
    h1i[kb] = r;
  }
  i32x4 bias1 = {0, 0, 0, 0};
  if (h == 0) bias1[0] = 0x3f80;   // h1[k=400] = 1.0 (bf16) for every edge

  // ---- fc2: 7 ntiles of 32 neurons; weights via LDS; h2 packed in regs ----
  int p2[7][8];
  for (int nt = 0; nt < 7; nt++) {
    if (nt) __syncthreads();                    // prev tile's reads complete
    for (int kb = w; kb < 26; kb += 4) {        // stage 26 KB, coalesced
      i32x4 v = *(const i32x4*)(W2f + (((size_t)nt * 26 + kb) * 64 + l) * 8);
      *(i32x4*)&wsm[kb * 512 + l * 8] = v;
    }
    __syncthreads();
    f32x16 acc = {0.f,0.f,0.f,0.f,0.f,0.f,0.f,0.f,0.f,0.f,0.f,0.f,0.f,0.f,0.f,0.f};
    #pragma unroll
    for (int kb = 0; kb < 25; kb++) {
      bf16x8 a = *(const bf16x8*)&wsm[kb * 512 + l * 8];
      acc = __builtin_amdgcn_mfma_f32_32x32x16_bf16(
          a, __builtin_bit_cast(bf16x8, h1i[kb]), acc, 0, 0, 0);
    }
    {  // kb = 25: bias column k=400
      bf16x8 a = *(const bf16x8*)&wsm[25 * 512 + l * 8];
      acc = __builtin_amdgcn_mfma_f32_32x32x16_bf16(
          a, __builtin_bit_cast(bf16x8, bias1), acc, 0, 0, 0);
    }
    #pragma unroll
    for (int q = 0; q < 8; q++) {   // relu + RNE-pack regs (2q, 2q+1)
      float v0 = fmaxf(acc[2 * q], 0.f);
      float v1 = fmaxf(acc[2 * q + 1], 0.f);
      unsigned u0 = __float_as_uint(v0); u0 += 0x7fffu + ((u0 >> 16) & 1u);
      unsigned u1 = __float_as_uint(v1); u1 += 0x7fffu + ((u1 >> 16) & 1u);
      p2[nt][q] = (int)((u0 >> 16) | (u1 & 0xFFFF0000u));
    }
  }

  // ---- transpose: C-layout h2 -> fc3 B-frags via shfl_xor(32) -------------
  i32x4 b2f[14];
  #pragma unroll
  for (int kb3 = 0; kb3 < 14; kb3++) {
    int nt = kb3 >> 1;
    i32x4 f;
    #pragma unroll
    for (int jj = 0; jj < 4; jj++) {
      int q0 = (jj & 1) + 4 * (kb3 & 1);
      if (jj < 2) {        // source lives in lower half (h_s = 0)
        int x = __shfl_xor(p2[nt][q0 + 2], 32);
        f[jj] = h ? x : p2[nt][q0];
      } else {             // source lives in upper half (h_s = 1)
        int y = __shfl_xor(p2[nt][q0], 32);
        f[jj] = h ? p2[nt][q0 + 2] : y;
      }
    }
    if (kb3 == 12 && h) f[0] |= 0x3f80;   // h2[k2=200] = 1.0 (fc3 bias-one)
    b2f[kb3] = f;
  }

  // ---- fc3 + fc4 ----------------------------------------------------------
  float osum = 0.f;
  for (int nt3 = 0; nt3 < 4; nt3++) {
    __syncthreads();                            // prev tile's reads complete
    for (int kb = w; kb < 14; kb += 4) {        // stage 14 KB
      i32x4 v = *(const i32x4*)(W3f + (((size_t)nt3 * 14 + kb) * 64 + l) * 8);
      *(i32x4*)&wsm[kb * 512 + l * 8] = v;
    }
    __syncthreads();
    f32x16 acc = {0.f,0.f,0.f,0.f,0.f,0.f,0.f,0.f,0.f,0.f,0.f,0.f,0.f,0.f,0.f,0.f};
    #pragma unroll
    for (int kb3 = 0; kb3 < 14; kb3++) {
      bf16x8 a = *(const bf16x8*)&wsm[kb3 * 512 + l * 8];
      acc = __builtin_amdgcn_mfma_f32_32x32x16_bf16(
          a, __builtin_bit_cast(bf16x8, b2f[kb3]), acc, 0, 0, 0);
    }
    #pragma unroll
    for (int r = 0; r < 16; r++) {
      int rho = (r & 3) + 8 * (r >> 2) + 4 * h + 32 * nt3;
      osum += fmaxf(acc[r], 0.f) * fc4wp[rho];   // pad rows: 0 * 0
    }
  }
  osum += __shfl_xor(osum, 32);     // combine the two k-halves of this edge
  if (h == 0 && e < NE) out[e] = osum + fc4b[0];
}

// ---------------------------------------------------------------------------
extern "C" void kernel_launch(void* const* d_in, const int* in_sizes, int n_in,
                              void* d_out, int out_size, void* d_ws, size_t ws_size,
                              hipStream_t stream) {
  (void)in_sizes; (void)n_in; (void)out_size; (void)ws_size;
  const float* z    = (const float*)d_in[0];
  const int*   ei   = (const int*)d_in[1];
  const float* cell = (const float*)d_in[2];
  const float* esm  = (const float*)d_in[3];
  const float* w1   = (const float*)d_in[4];
  const float* b1   = (const float*)d_in[5];
  const float* w2   = (const float*)d_in[6];
  const float* b2   = (const float*)d_in[7];
  const float* w3   = (const float*)d_in[8];
  const float* b3   = (const float*)d_in[9];
  const float* fc1w = (const float*)d_in[10];
  const float* fc1b = (const float*)d_in[11];
  const float* fc2w = (const float*)d_in[12];
  const float* fc2b = (const float*)d_in[13];
  const float* fc3w = (const float*)d_in[14];
  const float* fc3b = (const float*)d_in[15];
  const float* fc4w = (const float*)d_in[16];
  const float* fc4b = (const float*)d_in[17];
  float* out = (float*)d_out;

  // workspace layout (u16 units, all 16B-aligned): ~49.6 MB
  u16* zc  = (u16*)d_ws;                        // NNP*416
  u16* PQ  = zc  + (size_t)NNP * KD;            // NNP*800
  u16* W1f = PQ  + (size_t)NNP * 800;           // 332800
  u16* W2f = W1f + W1F_ELEMS;                   // 93184
  u16* W3f = W2f + W2F_ELEMS;                   // 28672
  float* fc4wp = (float*)(W3f + W3F_ELEMS);     // 128 f32

  prep_w<<<(PREP_TOT + 255) / 256, 256, 0, stream>>>(
      fc1w, fc1b, fc2w, fc2b, fc3w, fc3b, fc4w, W1f, W2f, W3f, fc4wp);
  build_zc<<<NNP / 4, 256, 0, stream>>>(z, cell, esm, w1, b1, w2, b2, w3, b3, zc);
  node_gemm<<<dim3((NNP + 127) / 128, 2), 256, 0, stream>>>(zc, W1f, PQ);
  edge_kernel<<<(NE + 127) / 128, 256, 0, stream>>>(PQ, W2f, W3f, fc4wp, fc4b, ei, out);
}